// Round 6
// baseline (233.188 us; speedup 1.0000x reference)
//
#include <hip/hip_runtime.h>

typedef __bf16 bf16;
typedef __bf16 bf16x8 __attribute__((ext_vector_type(8)));
typedef __bf16 bf16x4 __attribute__((ext_vector_type(4)));
typedef short s16x4 __attribute__((ext_vector_type(4)));
typedef float f32x4 __attribute__((ext_vector_type(4)));

static constexpr int NB = 4;       // batch
static constexpr int NS = 2048;    // seq
static constexpr int ND = 1024;    // model dim
static constexpr int NH = 16;      // heads
static constexpr int HD = 64;      // head dim
static constexpr float QSCALE = 0.18033688011112042f;  // log2(e)/sqrt(64)

// async global->LDS, 16B per lane; LDS dest = wave-uniform base + lane*16
#define GL16(g, l)                                                             \
    __builtin_amdgcn_global_load_lds(                                          \
        (const __attribute__((address_space(1))) void*)(g),                    \
        (__attribute__((address_space(3))) void*)(l), 16, 0, 0)

// pack 2 f32 -> u32 of 2 bf16 (compiler fuses to v_cvt_pk_bf16_f32)
static __device__ __forceinline__ unsigned pk2(float a, float b) {
    union { __bf16 h[2]; unsigned u; } t;
    t.h[0] = (__bf16)a; t.h[1] = (__bf16)b;
    return t.u;
}

// ---------------- convert f32 -> bf16 (vectorized) ----------------
__global__ void k_conv(const float* __restrict__ in, bf16* __restrict__ out, int n) {
    int i = (blockIdx.x * blockDim.x + threadIdx.x) * 4;
    if (i < n) {
        float4 v = *reinterpret_cast<const float4*>(in + i);
        bf16* o = out + i;
        o[0] = (bf16)v.x; o[1] = (bf16)v.y; o[2] = (bf16)v.z; o[3] = (bf16)v.w;
    }
}

// ------------- transpose + convert: in[K][N] f32 -> out[N][K] bf16 -------------
__global__ void k_transconv(const float* __restrict__ in, bf16* __restrict__ out,
                            int K, int N) {
    __shared__ float tile[32][33];
    int k0 = blockIdx.y * 32, n0 = blockIdx.x * 32;
    int tx = threadIdx.x, ty = threadIdx.y;  // block (32,8)
    for (int j = 0; j < 32; j += 8)
        tile[ty + j][tx] = in[(long)(k0 + ty + j) * N + n0 + tx];
    __syncthreads();
    for (int j = 0; j < 32; j += 8)
        out[(long)(n0 + ty + j) * K + k0 + tx] = (bf16)tile[tx][ty + j];
}

// ---------------- MFMA GEMM, 2-phase double-buffered (T3-min recipe) ----------
template <int EPI>
__global__ __launch_bounds__(256, 2) void k_gemm(
    const bf16* __restrict__ A, const bf16* __restrict__ Bt,
    const float* __restrict__ bias,
    void* __restrict__ out0, void* __restrict__ out1, void* __restrict__ out2,
    int M, int N, int Kd)
{
    constexpr int BM = 128, BN = 128, BK = 64;
    __shared__ __align__(16) bf16 As[2][BM * BK];
    __shared__ __align__(16) bf16 Bs[2][BN * BK];

    const int t = threadIdx.x;
    const int wid = t >> 6, lane = t & 63;
    const int wm = wid >> 1, wn = wid & 1;
    const int m0 = blockIdx.y * BM, n0 = blockIdx.x * BN;
    const int lrow = lane & 15, lhi = lane >> 4;

    const int srow0 = wid * 32 + (lane >> 3);
    const int scol = ((lane & 7) ^ (lane >> 3)) * 8;
    const bf16* ag = A + (long)(m0 + srow0) * Kd + scol;
    const bf16* bg = Bt + (long)(n0 + srow0) * Kd + scol;

    auto STAGE = [&](int buf_, int k0_) {
#pragma unroll
        for (int c = 0; c < 4; ++c) {
            GL16(ag + (long)(c * 8) * Kd + k0_, &As[buf_][(wid * 32 + c * 8) * BK]);
            GL16(bg + (long)(c * 8) * Kd + k0_, &Bs[buf_][(wid * 32 + c * 8) * BK]);
        }
    };

    f32x4 acc[4][4] = {};
    const int nt = Kd >> 6;
    const int swzr = (lrow & 7) << 4;
    int co[2];
#pragma unroll
    for (int kk = 0; kk < 2; ++kk)
        co[kk] = ((kk * 64 + lhi * 16) ^ swzr) >> 1;

    STAGE(0, 0);
    __syncthreads();
    int cur = 0;
    for (int tix = 0; tix < nt; ++tix) {
        if (tix + 1 < nt) STAGE(cur ^ 1, (tix + 1) * BK);

        bf16x8 af[2][4], bfr[2][4];
#pragma unroll
        for (int kk = 0; kk < 2; ++kk)
#pragma unroll
            for (int i = 0; i < 4; ++i) {
                af[kk][i]  = *reinterpret_cast<const bf16x8*>(
                    &As[cur][(wm * 64 + i * 16 + lrow) * BK + co[kk]]);
                bfr[kk][i] = *reinterpret_cast<const bf16x8*>(
                    &Bs[cur][(wn * 64 + i * 16 + lrow) * BK + co[kk]]);
            }
        __builtin_amdgcn_s_setprio(1);
#pragma unroll
        for (int kk = 0; kk < 2; ++kk)
#pragma unroll
            for (int i = 0; i < 4; ++i)
#pragma unroll
                for (int j = 0; j < 4; ++j)
                    acc[i][j] = __builtin_amdgcn_mfma_f32_16x16x32_bf16(
                        af[kk][i], bfr[kk][j], acc[i][j], 0, 0, 0);
        __builtin_amdgcn_s_setprio(0);
        __syncthreads();
        cur ^= 1;
    }

    if (EPI == 0) {
        bf16* Qb = (bf16*)out0; bf16* Kb = (bf16*)out1; bf16* Vt = (bf16*)out2;
#pragma unroll
        for (int j = 0; j < 4; ++j) {
            int col = n0 + wn * 64 + j * 16 + lrow;
            float bv = bias[col];
            int which = col >> 10;          // 0:q 1:k 2:v
            int rem = col & 1023;
            int h = rem >> 6, d = rem & 63;
#pragma unroll
            for (int i = 0; i < 4; ++i) {
                int mbase = m0 + wm * 64 + i * 16 + lhi * 4;
#pragma unroll
                for (int r = 0; r < 4; ++r) {
                    int row = mbase + r;
                    int bb = row >> 11, s = row & 2047;
                    long bh = bb * NH + h;
                    float v = acc[i][j][r] + bv;
                    if (which == 0)      Qb[(bh * NS + s) * HD + d] = (bf16)(v * QSCALE);
                    else if (which == 1) Kb[(bh * NS + s) * HD + d] = (bf16)v;
                    else                 Vt[(bh * HD + d) * NS + s] = (bf16)v;
                }
            }
        }
    } else {
        float* O = (float*)out0;
#pragma unroll
        for (int j = 0; j < 4; ++j) {
            int col = n0 + wn * 64 + j * 16 + lrow;
            float bv = bias[col];
#pragma unroll
            for (int i = 0; i < 4; ++i) {
                int mbase = m0 + wm * 64 + i * 16 + lhi * 4;
#pragma unroll
                for (int r = 0; r < 4; ++r)
                    O[(long)(mbase + r) * N + col] = acc[i][j][r] + bv;
            }
        }
    }
}

// ---------------- flash attention v3: zero-shuffle PV via 16x16x16 MFMA ------
// Swapped QK^T (D-layout: col=q, keys 4*lhi+r) feeds PV's B-operand DIRECTLY:
// O^T = V^T * P^T with mfma_f32_16x16x16bf16_1k (B-frag k-grain = 4 = D grain).
// 32 q/wave (2 frags) halves LDS reads per FLOP. global_load_lds staging with
// pre-swizzled source, 2-phase double buffer, 1 barrier/tile. LDS 32 KB.
__global__ __launch_bounds__(256, 4) void k_attn(
    const bf16* __restrict__ Qb, const bf16* __restrict__ Kb,
    const bf16* __restrict__ Vt, bf16* __restrict__ Ao)
{
    constexpr int KB = 64;
    constexpr int NT = NS / KB;   // 32 tiles
    __shared__ __align__(16) bf16 Ks[2][KB * HD];   // row=key, 128B, XOR-swizzled
    __shared__ __align__(16) bf16 Vs[2][HD * KB];   // row=d,   128B, XOR-swizzled

    const int t = threadIdx.x;
    const int wid = t >> 6, lane = t & 63;
    const int lrow = lane & 15, lhi = lane >> 4;

    // bijective XCD swizzle: 1024 blocks, 8 XCDs, 128 contiguous per XCD
    const int flat = blockIdx.y * gridDim.x + blockIdx.x;
    const int n = (flat & 7) * 128 + (flat >> 3);
    const int bh = n >> 4;
    const int qblk = (n & 15) * 128;
    const int qw = qblk + wid * 32;        // wave's 32 q rows

    const bf16* Qg = Qb + ((long)bh * NS + qw) * HD;
    const bf16* Kg = Kb + (long)bh * NS * HD;
    const bf16* Vg = Vt + (long)bh * HD * NS;

    // Q fragments (B-operand of QK): q = qfr*16 + lrow, k contiguous
    bf16x8 qf[2][2];
#pragma unroll
    for (int qfr = 0; qfr < 2; ++qfr)
#pragma unroll
        for (int c = 0; c < 2; ++c)
            qf[qfr][c] = *reinterpret_cast<const bf16x8*>(
                Qg + (long)(qfr * 16 + lrow) * HD + c * 32 + lhi * 8);

    f32x4 of[2][4] = {};
    float lsum[2] = {0.f, 0.f};

    // staging via global_load_lds, pre-swizzled source column
    const int gsr = lane >> 3;                       // row within 8-row group
    const int gsc = ((lane & 7) ^ gsr) * 8;          // swizzled elem col
    auto STAGE = [&](int buf, int kb) {
#pragma unroll
        for (int c = 0; c < 2; ++c) {
            const int rb = wid * 16 + c * 8;
            GL16(Kg + (long)(kb + rb + gsr) * HD + gsc, &Ks[buf][rb * 64]);
            GL16(Vg + (long)(rb + gsr) * NS + kb + gsc, &Vs[buf][rb * 64]);
        }
    };

    const int rsw = (lrow & 7) << 4;   // read-side XOR (bytes), row&7 == lrow&7

#define COMPUTE(b_, i_)                                                        \
    {                                                                          \
        f32x4 st[2][4] = {};                                                   \
        __builtin_amdgcn_s_setprio(1);                                         \
        _Pragma("unroll")                                                      \
        for (int j = 0; j < 4; ++j) {                                          \
            _Pragma("unroll")                                                  \
            for (int c = 0; c < 2; ++c) {                                      \
                bf16x8 kf = *reinterpret_cast<const bf16x8*>(                  \
                    &Ks[b_][(j * 16 + lrow) * 64 +                             \
                            (((c * 64 + lhi * 16) ^ rsw) >> 1)]);              \
                _Pragma("unroll")                                              \
                for (int qfr = 0; qfr < 2; ++qfr)                              \
                    st[qfr][j] = __builtin_amdgcn_mfma_f32_16x16x32_bf16(      \
                        kf, qf[qfr][c], st[qfr][j], 0, 0, 0);                  \
            }                                                                  \
        }                                                                      \
        __builtin_amdgcn_s_setprio(0);                                         \
        union { unsigned u[2]; s16x4 s; } pf[2][4];                            \
        _Pragma("unroll")                                                      \
        for (int qfr = 0; qfr < 2; ++qfr)                                      \
            _Pragma("unroll")                                                  \
            for (int j = 0; j < 4; ++j) {                                      \
                float e0 = __builtin_amdgcn_exp2f(st[qfr][j][0]);              \
                float e1 = __builtin_amdgcn_exp2f(st[qfr][j][1]);              \
                float e2 = __builtin_amdgcn_exp2f(st[qfr][j][2]);              \
                float e3 = __builtin_amdgcn_exp2f(st[qfr][j][3]);              \
                lsum[qfr] += (e0 + e1) + (e2 + e3);                            \
                pf[qfr][j].u[0] = pk2(e0, e1);                                 \
                pf[qfr][j].u[1] = pk2(e2, e3);                                 \
            }                                                                  \
        __builtin_amdgcn_s_setprio(1);                                         \
        _Pragma("unroll")                                                      \
        for (int j = 0; j < 4; ++j) {                                          \
            _Pragma("unroll")                                                  \
            for (int f = 0; f < 4; ++f) {                                      \
                s16x4 vf = *reinterpret_cast<const s16x4*>(                    \
                    &Vs[b_][(f * 16 + lrow) * 64 +                             \
                            (((j * 32 + lhi * 8) ^ rsw) >> 1)]);               \
                _Pragma("unroll")                                              \
                for (int qfr = 0; qfr < 2; ++qfr)                              \
                    of[qfr][f] = __builtin_amdgcn_mfma_f32_16x16x16bf16_1k(    \
                        vf, pf[qfr][j].s, of[qfr][f], 0, 0, 0);                \
            }                                                                  \
        }                                                                      \
        __builtin_amdgcn_s_setprio(0);                                         \
    }

    STAGE(0, 0);
    for (int it = 0; it < NT; it += 2) {
        __syncthreads();                 // buf0 ready (vmcnt drained by compiler)
        STAGE(1, (it + 1) * KB);
        COMPUTE(0, it);
        __syncthreads();                 // buf1 ready
        if (it + 2 < NT) STAGE(0, (it + 2) * KB);
        COMPUTE(1, it + 1);
    }
#undef COMPUTE

    // l lives per lane for q = lrow (replicated over lhi after reduce)
#pragma unroll
    for (int qfr = 0; qfr < 2; ++qfr) {
        lsum[qfr] += __shfl_xor(lsum[qfr], 16);
        lsum[qfr] += __shfl_xor(lsum[qfr], 32);
    }

    const int bb = bh >> 4, h = bh & 15;
#pragma unroll
    for (int qfr = 0; qfr < 2; ++qfr) {
        float inv = 1.0f / lsum[qfr];
        int s = qw + qfr * 16 + lrow;
#pragma unroll
        for (int f = 0; f < 4; ++f) {
            bf16x4 o4;
#pragma unroll
            for (int r = 0; r < 4; ++r) o4[r] = (bf16)(of[qfr][f][r] * inv);
            *reinterpret_cast<bf16x4*>(
                &Ao[((long)bb * NS + s) * ND + h * HD + f * 16 + 4 * lhi]) = o4;
        }
    }
}

// ---------------- launch ----------------
extern "C" void kernel_launch(void* const* d_in, const int* in_sizes, int n_in,
                              void* d_out, int out_size, void* d_ws, size_t ws_size,
                              hipStream_t stream) {
    const float* x    = (const float*)d_in[0];
    const float* Wqkv = (const float*)d_in[1];
    const float* bqkv = (const float*)d_in[2];
    const float* Wout = (const float*)d_in[3];
    const float* bout = (const float*)d_in[4];
    float* out = (float*)d_out;

    char* ws = (char*)d_ws;
    bf16* Xb  = (bf16*)(ws);                         // 16.78 MB
    bf16* Wqt = (bf16*)(ws + 16777216);              //  6.29 MB
    bf16* Wot = (bf16*)(ws + 23068672);              //  2.10 MB
    bf16* Qb  = (bf16*)(ws + 25165824);              // 16.78 MB
    bf16* Kb  = (bf16*)(ws + 41943040);              // 16.78 MB
    bf16* Vt  = (bf16*)(ws + 58720256);              // 16.78 MB
    bf16* Ab  = (bf16*)(ws + 75497472);              // 16.78 MB  (total ~92 MB)

    k_conv<<<dim3(8192), dim3(256), 0, stream>>>(x, Xb, NB * NS * ND);
    k_transconv<<<dim3(96, 32), dim3(32, 8), 0, stream>>>(Wqkv, Wqt, ND, 3 * ND);
    k_transconv<<<dim3(32, 32), dim3(32, 8), 0, stream>>>(Wout, Wot, ND, ND);

    k_gemm<0><<<dim3(24, 64), dim3(256), 0, stream>>>(
        Xb, Wqt, bqkv, Qb, Kb, Vt, NB * NS, 3 * ND, ND);

    k_attn<<<dim3(16, 64), dim3(256), 0, stream>>>(Qb, Kb, Vt, Ab);

    k_gemm<1><<<dim3(8, 64), dim3(256), 0, stream>>>(
        Ab, Wot, bout, out, nullptr, nullptr, NB * NS, ND, ND);
}

// Round 7
// 221.520 us; speedup vs baseline: 1.0527x; 1.0527x over previous
//
#include <hip/hip_runtime.h>

typedef __bf16 bf16;
typedef __bf16 bf16x8 __attribute__((ext_vector_type(8)));
typedef float f32x4 __attribute__((ext_vector_type(4)));
typedef unsigned u32x2 __attribute__((ext_vector_type(2)));

static constexpr int NB = 4;       // batch
static constexpr int NS = 2048;    // seq
static constexpr int ND = 1024;    // model dim
static constexpr int NH = 16;      // heads
static constexpr int HD = 64;      // head dim
static constexpr float QSCALE = 0.18033688011112042f;  // log2(e)/sqrt(64)

// async global->LDS, 16B per lane; LDS dest = wave-uniform base + lane*16
#define GL16(g, l)                                                             \
    __builtin_amdgcn_global_load_lds(                                          \
        (const __attribute__((address_space(1))) void*)(g),                    \
        (__attribute__((address_space(3))) void*)(l), 16, 0, 0)

// pack 2 f32 -> u32 of 2 bf16 (compiler fuses to v_cvt_pk_bf16_f32)
static __device__ __forceinline__ unsigned pk2(float a, float b) {
    union { __bf16 h[2]; unsigned u; } t;
    t.h[0] = (__bf16)a; t.h[1] = (__bf16)b;
    return t.u;
}

// ---------------- convert f32 -> bf16 (vectorized) ----------------
__global__ void k_conv(const float* __restrict__ in, bf16* __restrict__ out, int n) {
    int i = (blockIdx.x * blockDim.x + threadIdx.x) * 4;
    if (i < n) {
        float4 v = *reinterpret_cast<const float4*>(in + i);
        bf16* o = out + i;
        o[0] = (bf16)v.x; o[1] = (bf16)v.y; o[2] = (bf16)v.z; o[3] = (bf16)v.w;
    }
}

// ------------- transpose + convert: in[K][N] f32 -> out[N][K] bf16 -------------
__global__ void k_transconv(const float* __restrict__ in, bf16* __restrict__ out,
                            int K, int N) {
    __shared__ float tile[32][33];
    int k0 = blockIdx.y * 32, n0 = blockIdx.x * 32;
    int tx = threadIdx.x, ty = threadIdx.y;  // block (32,8)
    for (int j = 0; j < 32; j += 8)
        tile[ty + j][tx] = in[(long)(k0 + ty + j) * N + n0 + tx];
    __syncthreads();
    for (int j = 0; j < 32; j += 8)
        out[(long)(n0 + ty + j) * K + k0 + tx] = (bf16)tile[tx][ty + j];
}

// ---------------- MFMA GEMM, 2-phase double-buffered (T3-min recipe) ----------
template <int EPI>
__global__ __launch_bounds__(256, 2) void k_gemm(
    const bf16* __restrict__ A, const bf16* __restrict__ Bt,
    const float* __restrict__ bias,
    void* __restrict__ out0, void* __restrict__ out1, void* __restrict__ out2,
    int M, int N, int Kd)
{
    constexpr int BM = 128, BN = 128, BK = 64;
    __shared__ __align__(16) bf16 As[2][BM * BK];
    __shared__ __align__(16) bf16 Bs[2][BN * BK];

    const int t = threadIdx.x;
    const int wid = t >> 6, lane = t & 63;
    const int wm = wid >> 1, wn = wid & 1;
    const int m0 = blockIdx.y * BM, n0 = blockIdx.x * BN;
    const int lrow = lane & 15, lhi = lane >> 4;

    const int srow0 = wid * 32 + (lane >> 3);
    const int scol = ((lane & 7) ^ (lane >> 3)) * 8;
    const bf16* ag = A + (long)(m0 + srow0) * Kd + scol;
    const bf16* bg = Bt + (long)(n0 + srow0) * Kd + scol;

    auto STAGE = [&](int buf_, int k0_) {
#pragma unroll
        for (int c = 0; c < 4; ++c) {
            GL16(ag + (long)(c * 8) * Kd + k0_, &As[buf_][(wid * 32 + c * 8) * BK]);
            GL16(bg + (long)(c * 8) * Kd + k0_, &Bs[buf_][(wid * 32 + c * 8) * BK]);
        }
    };

    f32x4 acc[4][4] = {};
    const int nt = Kd >> 6;
    const int swzr = (lrow & 7) << 4;
    int co[2];
#pragma unroll
    for (int kk = 0; kk < 2; ++kk)
        co[kk] = ((kk * 64 + lhi * 16) ^ swzr) >> 1;

    STAGE(0, 0);
    __syncthreads();
    int cur = 0;
    for (int tix = 0; tix < nt; ++tix) {
        if (tix + 1 < nt) STAGE(cur ^ 1, (tix + 1) * BK);

        bf16x8 af[2][4], bfr[2][4];
#pragma unroll
        for (int kk = 0; kk < 2; ++kk)
#pragma unroll
            for (int i = 0; i < 4; ++i) {
                af[kk][i]  = *reinterpret_cast<const bf16x8*>(
                    &As[cur][(wm * 64 + i * 16 + lrow) * BK + co[kk]]);
                bfr[kk][i] = *reinterpret_cast<const bf16x8*>(
                    &Bs[cur][(wn * 64 + i * 16 + lrow) * BK + co[kk]]);
            }
        __builtin_amdgcn_s_setprio(1);
#pragma unroll
        for (int kk = 0; kk < 2; ++kk)
#pragma unroll
            for (int i = 0; i < 4; ++i)
#pragma unroll
                for (int j = 0; j < 4; ++j)
                    acc[i][j] = __builtin_amdgcn_mfma_f32_16x16x32_bf16(
                        af[kk][i], bfr[kk][j], acc[i][j], 0, 0, 0);
        __builtin_amdgcn_s_setprio(0);
        __syncthreads();
        cur ^= 1;
    }

    if (EPI == 0) {
        bf16* Qb = (bf16*)out0; bf16* Kb = (bf16*)out1; bf16* Vt = (bf16*)out2;
#pragma unroll
        for (int j = 0; j < 4; ++j) {
            int col = n0 + wn * 64 + j * 16 + lrow;
            float bv = bias[col];
            int which = col >> 10;          // 0:q 1:k 2:v
            int rem = col & 1023;
            int h = rem >> 6, d = rem & 63;
#pragma unroll
            for (int i = 0; i < 4; ++i) {
                int mbase = m0 + wm * 64 + i * 16 + lhi * 4;
#pragma unroll
                for (int r = 0; r < 4; ++r) {
                    int row = mbase + r;
                    int bb = row >> 11, s = row & 2047;
                    long bh = bb * NH + h;
                    float v = acc[i][j][r] + bv;
                    if (which == 0)      Qb[(bh * NS + s) * HD + d] = (bf16)(v * QSCALE);
                    else if (which == 1) Kb[(bh * NS + s) * HD + d] = (bf16)v;
                    else                 Vt[(bh * HD + d) * NS + s] = (bf16)v;
                }
            }
        }
    } else {
        float* O = (float*)out0;
#pragma unroll
        for (int j = 0; j < 4; ++j) {
            int col = n0 + wn * 64 + j * 16 + lrow;
            float bv = bias[col];
#pragma unroll
            for (int i = 0; i < 4; ++i) {
                int mbase = m0 + wm * 64 + i * 16 + lhi * 4;
#pragma unroll
                for (int r = 0; r < 4; ++r)
                    O[(long)(mbase + r) * N + col] = acc[i][j][r] + bv;
            }
        }
    }
}

// ---------------- flash attention v4: 32 q/wave, swizzled Ps, 40KB LDS -------
// Swapped QK^T, all MFMAs 16x16x32. P goes through an 8KB XOR-swizzled LDS
// buffer (write 8B / read 16B, zero-conflict involution), reused sequentially
// by the two 16-row q-fragments (same-wave LDS ops are in-order).
// K/V staged via global_load_lds (pre-swizzled source), 2-phase double buffer.
// LDS = 2*8K (K) + 2*8K (V) + 8K (Ps) = 40960 B -> 4 blocks/CU.
__global__ __launch_bounds__(256, 4) void k_attn(
    const bf16* __restrict__ Qb, const bf16* __restrict__ Kb,
    const bf16* __restrict__ Vt, bf16* __restrict__ Ao)
{
    constexpr int KB = 64;
    constexpr int NT = NS / KB;   // 32 tiles
    __shared__ __align__(16) bf16 Ks[2][KB * HD];   // row=key, 128B, swizzled
    __shared__ __align__(16) bf16 Vs[2][HD * KB];   // row=d,   128B, swizzled
    __shared__ __align__(16) bf16 Ps[4 * 16 * 64];  // per-wave 16q x 64k, swizzled

    const int t = threadIdx.x;
    const int wid = t >> 6, lane = t & 63;
    const int lrow = lane & 15, lhi = lane >> 4;

    // bijective XCD swizzle: 1024 blocks, 8 XCDs, 128 contiguous per XCD
    const int flat = blockIdx.y * gridDim.x + blockIdx.x;
    const int n = (flat & 7) * 128 + (flat >> 3);
    const int bh = n >> 4;
    const int qw = (n & 15) * 128 + wid * 32;   // wave's 32 q rows

    const bf16* Qg = Qb + ((long)bh * NS + qw) * HD;
    const bf16* Kg = Kb + (long)bh * NS * HD;
    const bf16* Vg = Vt + (long)bh * HD * NS;

    // Q fragments (B-operand of QK): q = qfr*16 + lrow, k contiguous
    bf16x8 qf[2][2];
#pragma unroll
    for (int qfr = 0; qfr < 2; ++qfr)
#pragma unroll
        for (int c = 0; c < 2; ++c)
            qf[qfr][c] = *reinterpret_cast<const bf16x8*>(
                Qg + (long)(qfr * 16 + lrow) * HD + c * 32 + lhi * 8);

    f32x4 of[2][4] = {};
    float lsum[2] = {0.f, 0.f};

    // staging via global_load_lds, pre-swizzled source column
    const int gsr = lane >> 3;                       // row within 8-row group
    const int gsc = ((lane & 7) ^ gsr) * 8;          // swizzled elem col
    auto STAGE = [&](int buf, int kb) {
#pragma unroll
        for (int c = 0; c < 2; ++c) {
            const int rb = wid * 16 + c * 8;
            GL16(Kg + (long)(kb + rb + gsr) * HD + gsc, &Ks[buf][rb * 64]);
            GL16(Vg + (long)(rb + gsr) * NS + kb + gsc, &Vs[buf][rb * 64]);
        }
    };

    const int rsw = (lrow & 7) << 4;          // read-side XOR (bytes)
    bf16* psw = &Ps[wid * 1024 + lrow * 64];  // wave-private P row base

    auto COMPUTE = [&](int b_) {
        // QK: S^T = K * Q^T. D: col=q(lrow), row=key j*16+4*lhi+r
        f32x4 st[2][4] = {};
        __builtin_amdgcn_s_setprio(1);
#pragma unroll
        for (int j = 0; j < 4; ++j)
#pragma unroll
            for (int c = 0; c < 2; ++c) {
                bf16x8 kf = *reinterpret_cast<const bf16x8*>(
                    &Ks[b_][(j * 16 + lrow) * 64 + (((c * 64 + lhi * 16) ^ rsw) >> 1)]);
#pragma unroll
                for (int qfr = 0; qfr < 2; ++qfr)
                    st[qfr][j] = __builtin_amdgcn_mfma_f32_16x16x32_bf16(
                        kf, qf[qfr][c], st[qfr][j], 0, 0, 0);
            }
        __builtin_amdgcn_s_setprio(0);

#pragma unroll
        for (int qfr = 0; qfr < 2; ++qfr) {
            // exp2 + l + pack keys 4lhi..4lhi+3 (8B) into swizzled Ps
#pragma unroll
            for (int j = 0; j < 4; ++j) {
                float e0 = __builtin_amdgcn_exp2f(st[qfr][j][0]);
                float e1 = __builtin_amdgcn_exp2f(st[qfr][j][1]);
                float e2 = __builtin_amdgcn_exp2f(st[qfr][j][2]);
                float e3 = __builtin_amdgcn_exp2f(st[qfr][j][3]);
                lsum[qfr] += (e0 + e1) + (e2 + e3);
                u32x2 w; w[0] = pk2(e0, e1); w[1] = pk2(e2, e3);
                *reinterpret_cast<u32x2*>(
                    reinterpret_cast<char*>(psw) + (((j * 32 + lhi * 8) ^ rsw))) = w;
            }
            asm volatile("" ::: "memory");   // order Ps writes vs reads (in-wave)
            // PV: O += P * V^T. A-frag = Ps (16B), B-frag = Vs (16B), both swizzled
#pragma unroll
            for (int chunk = 0; chunk < 2; ++chunk) {
                bf16x8 pf = *reinterpret_cast<const bf16x8*>(
                    reinterpret_cast<char*>(psw) + ((chunk * 64 + lhi * 16) ^ rsw));
                __builtin_amdgcn_s_setprio(1);
#pragma unroll
                for (int f = 0; f < 4; ++f) {
                    bf16x8 vf = *reinterpret_cast<const bf16x8*>(
                        &Vs[b_][(f * 16 + lrow) * 64 +
                                (((chunk * 64 + lhi * 16) ^ rsw) >> 1)]);
                    of[qfr][f] = __builtin_amdgcn_mfma_f32_16x16x32_bf16(
                        pf, vf, of[qfr][f], 0, 0, 0);
                }
                __builtin_amdgcn_s_setprio(0);
            }
            asm volatile("" ::: "memory");   // qfr0 reads before qfr1 writes
        }
    };

    STAGE(0, 0);
    for (int it = 0; it < NT; it += 2) {
        __syncthreads();                 // buf0 ready (vmcnt drained by compiler)
        STAGE(1, (it + 1) * KB);
        COMPUTE(0);
        __syncthreads();                 // buf1 ready
        if (it + 2 < NT) STAGE(0, (it + 2) * KB);
        COMPUTE(1);
    }

    // l reduction across lhi groups (lanes xor 16, 32) -> all lanes hold l(q=lrow)
#pragma unroll
    for (int qfr = 0; qfr < 2; ++qfr) {
        lsum[qfr] += __shfl_xor(lsum[qfr], 16);
        lsum[qfr] += __shfl_xor(lsum[qfr], 32);
    }

    const int bb = bh >> 4, h = bh & 15;
#pragma unroll
    for (int qfr = 0; qfr < 2; ++qfr) {
#pragma unroll
        for (int r = 0; r < 4; ++r) {
            float inv = 1.0f / __shfl(lsum[qfr], 4 * lhi + r);
            int s = qw + qfr * 16 + 4 * lhi + r;
#pragma unroll
            for (int f = 0; f < 4; ++f)
                Ao[((long)bb * NS + s) * ND + h * HD + f * 16 + lrow] =
                    (bf16)(of[qfr][f][r] * inv);
        }
    }
}

// ---------------- launch ----------------
extern "C" void kernel_launch(void* const* d_in, const int* in_sizes, int n_in,
                              void* d_out, int out_size, void* d_ws, size_t ws_size,
                              hipStream_t stream) {
    const float* x    = (const float*)d_in[0];
    const float* Wqkv = (const float*)d_in[1];
    const float* bqkv = (const float*)d_in[2];
    const float* Wout = (const float*)d_in[3];
    const float* bout = (const float*)d_in[4];
    float* out = (float*)d_out;

    char* ws = (char*)d_ws;
    bf16* Xb  = (bf16*)(ws);                         // 16.78 MB
    bf16* Wqt = (bf16*)(ws + 16777216);              //  6.29 MB
    bf16* Wot = (bf16*)(ws + 23068672);              //  2.10 MB
    bf16* Qb  = (bf16*)(ws + 25165824);              // 16.78 MB
    bf16* Kb  = (bf16*)(ws + 41943040);              // 16.78 MB
    bf16* Vt  = (bf16*)(ws + 58720256);              // 16.78 MB
    bf16* Ab  = (bf16*)(ws + 75497472);              // 16.78 MB  (total ~92 MB)

    k_conv<<<dim3(8192), dim3(256), 0, stream>>>(x, Xb, NB * NS * ND);
    k_transconv<<<dim3(96, 32), dim3(32, 8), 0, stream>>>(Wqkv, Wqt, ND, 3 * ND);
    k_transconv<<<dim3(32, 32), dim3(32, 8), 0, stream>>>(Wout, Wot, ND, ND);

    k_gemm<0><<<dim3(24, 64), dim3(256), 0, stream>>>(
        Xb, Wqt, bqkv, Qb, Kb, Vt, NB * NS, 3 * ND, ND);

    k_attn<<<dim3(16, 64), dim3(256), 0, stream>>>(Qb, Kb, Vt, Ab);

    k_gemm<1><<<dim3(8, 64), dim3(256), 0, stream>>>(
        Ab, Wot, bout, out, nullptr, nullptr, NB * NS, ND, ND);
}

// Round 8
// 219.454 us; speedup vs baseline: 1.0626x; 1.0094x over previous
//
#include <hip/hip_runtime.h>

typedef __bf16 bf16;
typedef __bf16 bf16x8 __attribute__((ext_vector_type(8)));
typedef float f32x4 __attribute__((ext_vector_type(4)));
typedef unsigned u32x2 __attribute__((ext_vector_type(2)));

static constexpr int NB = 4;       // batch
static constexpr int NS = 2048;    // seq
static constexpr int ND = 1024;    // model dim
static constexpr int NH = 16;      // heads
static constexpr int HD = 64;      // head dim
static constexpr float QSCALE = 0.18033688011112042f;  // log2(e)/sqrt(64)

// async global->LDS, 16B per lane; LDS dest = wave-uniform base + lane*16
#define GL16(g, l)                                                             \
    __builtin_amdgcn_global_load_lds(                                          \
        (const __attribute__((address_space(1))) void*)(g),                    \
        (__attribute__((address_space(3))) void*)(l), 16, 0, 0)

// pack 2 f32 -> u32 of 2 bf16 (compiler fuses to v_cvt_pk_bf16_f32)
static __device__ __forceinline__ unsigned pk2(float a, float b) {
    union { __bf16 h[2]; unsigned u; } t;
    t.h[0] = (__bf16)a; t.h[1] = (__bf16)b;
    return t.u;
}

// ---------------- convert f32 -> bf16 (vectorized) ----------------
__global__ void k_conv(const float* __restrict__ in, bf16* __restrict__ out, int n) {
    int i = (blockIdx.x * blockDim.x + threadIdx.x) * 4;
    if (i < n) {
        float4 v = *reinterpret_cast<const float4*>(in + i);
        bf16* o = out + i;
        o[0] = (bf16)v.x; o[1] = (bf16)v.y; o[2] = (bf16)v.z; o[3] = (bf16)v.w;
    }
}

// ------------- transpose + convert: in[K][N] f32 -> out[N][K] bf16 -------------
__global__ void k_transconv(const float* __restrict__ in, bf16* __restrict__ out,
                            int K, int N) {
    __shared__ float tile[32][33];
    int k0 = blockIdx.y * 32, n0 = blockIdx.x * 32;
    int tx = threadIdx.x, ty = threadIdx.y;  // block (32,8)
    for (int j = 0; j < 32; j += 8)
        tile[ty + j][tx] = in[(long)(k0 + ty + j) * N + n0 + tx];
    __syncthreads();
    for (int j = 0; j < 32; j += 8)
        out[(long)(n0 + ty + j) * K + k0 + tx] = (bf16)tile[tx][ty + j];
}

// ---------------- MFMA GEMM, 2-phase + counted vmcnt (T3+T4) ----------------
// Raw s_barrier + s_waitcnt vmcnt(8): prefetch loads stay in flight across
// barriers (no vmcnt(0) drain in steady state).
template <int EPI>
__global__ __launch_bounds__(256, 2) void k_gemm(
    const bf16* __restrict__ A, const bf16* __restrict__ Bt,
    const float* __restrict__ bias,
    void* __restrict__ out0, void* __restrict__ out1, void* __restrict__ out2,
    int M, int N, int Kd)
{
    constexpr int BM = 128, BN = 128, BK = 64;
    __shared__ __align__(16) bf16 As[2][BM * BK];
    __shared__ __align__(16) bf16 Bs[2][BN * BK];

    const int t = threadIdx.x;
    const int wid = t >> 6, lane = t & 63;
    const int wm = wid >> 1, wn = wid & 1;
    const int m0 = blockIdx.y * BM, n0 = blockIdx.x * BN;
    const int lrow = lane & 15, lhi = lane >> 4;

    const int srow0 = wid * 32 + (lane >> 3);
    const int scol = ((lane & 7) ^ (lane >> 3)) * 8;
    const bf16* ag = A + (long)(m0 + srow0) * Kd + scol;
    const bf16* bg = Bt + (long)(n0 + srow0) * Kd + scol;

    auto STAGE = [&](int buf_, int k0_) {
#pragma unroll
        for (int c = 0; c < 4; ++c) {
            GL16(ag + (long)(c * 8) * Kd + k0_, &As[buf_][(wid * 32 + c * 8) * BK]);
            GL16(bg + (long)(c * 8) * Kd + k0_, &Bs[buf_][(wid * 32 + c * 8) * BK]);
        }
    };

    f32x4 acc[4][4] = {};
    const int nt = Kd >> 6;
    const int swzr = (lrow & 7) << 4;
    int co[2];
#pragma unroll
    for (int kk = 0; kk < 2; ++kk)
        co[kk] = ((kk * 64 + lhi * 16) ^ swzr) >> 1;

    STAGE(0, 0);
    int cur = 0;
    for (int tix = 0; tix < nt; ++tix) {
        if (tix + 1 < nt) {
            STAGE(cur ^ 1, (tix + 1) * BK);
            asm volatile("s_waitcnt vmcnt(8)" ::: "memory");  // cur's 8 landed
        } else {
            asm volatile("s_waitcnt vmcnt(0)" ::: "memory");
        }
        __builtin_amdgcn_s_barrier();     // all waves' cur tile in LDS
        __builtin_amdgcn_sched_barrier(0);

        bf16x8 af[2][4], bfr[2][4];
#pragma unroll
        for (int kk = 0; kk < 2; ++kk)
#pragma unroll
            for (int i = 0; i < 4; ++i) {
                af[kk][i]  = *reinterpret_cast<const bf16x8*>(
                    &As[cur][(wm * 64 + i * 16 + lrow) * BK + co[kk]]);
                bfr[kk][i] = *reinterpret_cast<const bf16x8*>(
                    &Bs[cur][(wn * 64 + i * 16 + lrow) * BK + co[kk]]);
            }
        __builtin_amdgcn_s_setprio(1);
#pragma unroll
        for (int kk = 0; kk < 2; ++kk)
#pragma unroll
            for (int i = 0; i < 4; ++i)
#pragma unroll
                for (int j = 0; j < 4; ++j)
                    acc[i][j] = __builtin_amdgcn_mfma_f32_16x16x32_bf16(
                        af[kk][i], bfr[kk][j], acc[i][j], 0, 0, 0);
        __builtin_amdgcn_s_setprio(0);
        __builtin_amdgcn_s_barrier();     // all reads of cur done -> overwrite ok
        cur ^= 1;
    }

    if (EPI == 0) {
        bf16* Qb = (bf16*)out0; bf16* Kb = (bf16*)out1; bf16* Vt = (bf16*)out2;
#pragma unroll
        for (int j = 0; j < 4; ++j) {
            int col = n0 + wn * 64 + j * 16 + lrow;
            float bv = bias[col];
            int which = col >> 10;          // 0:q 1:k 2:v
            int rem = col & 1023;
            int h = rem >> 6, d = rem & 63;
#pragma unroll
            for (int i = 0; i < 4; ++i) {
                int mbase = m0 + wm * 64 + i * 16 + lhi * 4;
#pragma unroll
                for (int r = 0; r < 4; ++r) {
                    int row = mbase + r;
                    int bb = row >> 11, s = row & 2047;
                    long bh = bb * NH + h;
                    float v = acc[i][j][r] + bv;
                    if (which == 0)      Qb[(bh * NS + s) * HD + d] = (bf16)(v * QSCALE);
                    else if (which == 1) Kb[(bh * NS + s) * HD + d] = (bf16)v;
                    else                 Vt[(bh * HD + d) * NS + s] = (bf16)v;
                }
            }
        }
    } else {
        float* O = (float*)out0;
#pragma unroll
        for (int j = 0; j < 4; ++j) {
            int col = n0 + wn * 64 + j * 16 + lrow;
            float bv = bias[col];
#pragma unroll
            for (int i = 0; i < 4; ++i) {
                int mbase = m0 + wm * 64 + i * 16 + lhi * 4;
#pragma unroll
                for (int r = 0; r < 4; ++r)
                    O[(long)(mbase + r) * N + col] = acc[i][j][r] + bv;
            }
        }
    }
}

// ---------------- flash attention v5: V-hoist + counted vmcnt ----------------
// 32 q/wave, swapped QK^T, all MFMAs 16x16x32. P round-trips an 8KB swizzled
// LDS buffer; all 4 P-fragments are pulled into registers BEFORE one shared
// V sweep (V LDS reads halved). Raw s_barrier + vmcnt(4): staging loads stay
// in flight across barriers. LDS 40KB.
__global__ __launch_bounds__(256, 4) void k_attn(
    const bf16* __restrict__ Qb, const bf16* __restrict__ Kb,
    const bf16* __restrict__ Vt, bf16* __restrict__ Ao)
{
    constexpr int KB = 64;
    constexpr int NT = NS / KB;   // 32 tiles
    __shared__ __align__(16) bf16 Ks[2][KB * HD];   // row=key, 128B, swizzled
    __shared__ __align__(16) bf16 Vs[2][HD * KB];   // row=d,   128B, swizzled
    __shared__ __align__(16) bf16 Ps[4 * 16 * 64];  // per-wave 16q x 64k, swizzled

    const int t = threadIdx.x;
    const int wid = t >> 6, lane = t & 63;
    const int lrow = lane & 15, lhi = lane >> 4;

    // bijective XCD swizzle: 1024 blocks, 8 XCDs, 128 contiguous per XCD
    const int flat = blockIdx.y * gridDim.x + blockIdx.x;
    const int n = (flat & 7) * 128 + (flat >> 3);
    const int bh = n >> 4;
    const int qw = (n & 15) * 128 + wid * 32;   // wave's 32 q rows

    const bf16* Qg = Qb + ((long)bh * NS + qw) * HD;
    const bf16* Kg = Kb + (long)bh * NS * HD;
    const bf16* Vg = Vt + (long)bh * HD * NS;

    // Q fragments (B-operand of QK): q = qfr*16 + lrow, k contiguous
    bf16x8 qf[2][2];
#pragma unroll
    for (int qfr = 0; qfr < 2; ++qfr)
#pragma unroll
        for (int c = 0; c < 2; ++c)
            qf[qfr][c] = *reinterpret_cast<const bf16x8*>(
                Qg + (long)(qfr * 16 + lrow) * HD + c * 32 + lhi * 8);

    f32x4 of[2][4] = {};
    float lsum[2] = {0.f, 0.f};

    // staging via global_load_lds, pre-swizzled source column
    const int gsr = lane >> 3;                       // row within 8-row group
    const int gsc = ((lane & 7) ^ gsr) * 8;          // swizzled elem col
    auto STAGE = [&](int buf, int kb) {
#pragma unroll
        for (int c = 0; c < 2; ++c) {
            const int rb = wid * 16 + c * 8;
            GL16(Kg + (long)(kb + rb + gsr) * HD + gsc, &Ks[buf][rb * 64]);
            GL16(Vg + (long)(rb + gsr) * NS + kb + gsc, &Vs[buf][rb * 64]);
        }
    };

    const int rsw = (lrow & 7) << 4;          // read-side XOR (bytes)
    bf16* psw = &Ps[wid * 1024 + lrow * 64];  // wave-private P row base

    auto COMPUTE = [&](int b_) {
        // QK: S^T = K * Q^T. D: col=q(lrow), row=key j*16+4*lhi+r
        f32x4 st[2][4] = {};
        __builtin_amdgcn_s_setprio(1);
#pragma unroll
        for (int j = 0; j < 4; ++j)
#pragma unroll
            for (int c = 0; c < 2; ++c) {
                bf16x8 kf = *reinterpret_cast<const bf16x8*>(
                    &Ks[b_][(j * 16 + lrow) * 64 + (((c * 64 + lhi * 16) ^ rsw) >> 1)]);
#pragma unroll
                for (int qfr = 0; qfr < 2; ++qfr)
                    st[qfr][j] = __builtin_amdgcn_mfma_f32_16x16x32_bf16(
                        kf, qf[qfr][c], st[qfr][j], 0, 0, 0);
            }
        __builtin_amdgcn_s_setprio(0);

        // softmax + Ps round trip; all 4 P-fragments into registers
        bf16x8 pfr[2][2];
#pragma unroll
        for (int qfr = 0; qfr < 2; ++qfr) {
#pragma unroll
            for (int j = 0; j < 4; ++j) {
                float e0 = __builtin_amdgcn_exp2f(st[qfr][j][0]);
                float e1 = __builtin_amdgcn_exp2f(st[qfr][j][1]);
                float e2 = __builtin_amdgcn_exp2f(st[qfr][j][2]);
                float e3 = __builtin_amdgcn_exp2f(st[qfr][j][3]);
                lsum[qfr] += (e0 + e1) + (e2 + e3);
                u32x2 w; w[0] = pk2(e0, e1); w[1] = pk2(e2, e3);
                *reinterpret_cast<u32x2*>(
                    reinterpret_cast<char*>(psw) + (((j * 32 + lhi * 8) ^ rsw))) = w;
            }
            asm volatile("" ::: "memory");   // Ps writes before reads (in-wave)
#pragma unroll
            for (int chunk = 0; chunk < 2; ++chunk)
                pfr[qfr][chunk] = *reinterpret_cast<const bf16x8*>(
                    reinterpret_cast<char*>(psw) + ((chunk * 64 + lhi * 16) ^ rsw));
            asm volatile("" ::: "memory");   // qfr0 reads before qfr1 overwrites
        }

        // PV: single V sweep shared by both q-fragments
        __builtin_amdgcn_s_setprio(1);
#pragma unroll
        for (int chunk = 0; chunk < 2; ++chunk)
#pragma unroll
            for (int f = 0; f < 4; ++f) {
                bf16x8 vf = *reinterpret_cast<const bf16x8*>(
                    &Vs[b_][(f * 16 + lrow) * 64 +
                            (((chunk * 64 + lhi * 16) ^ rsw) >> 1)]);
#pragma unroll
                for (int qfr = 0; qfr < 2; ++qfr)
                    of[qfr][f] = __builtin_amdgcn_mfma_f32_16x16x32_bf16(
                        pfr[qfr][chunk], vf, of[qfr][f], 0, 0, 0);
            }
        __builtin_amdgcn_s_setprio(0);
    };

    STAGE(0, 0);
    int cur = 0;
    for (int it = 0; it < NT; ++it) {
        if (it + 1 < NT) {
            STAGE(cur ^ 1, (it + 1) * KB);
            asm volatile("s_waitcnt vmcnt(4)" ::: "memory");  // cur's 4 landed
        } else {
            asm volatile("s_waitcnt vmcnt(0)" ::: "memory");
        }
        __builtin_amdgcn_s_barrier();
        __builtin_amdgcn_sched_barrier(0);
        COMPUTE(cur);
        __builtin_amdgcn_s_barrier();     // reads of cur done -> overwrite ok
        cur ^= 1;
    }

    // l reduction across lhi groups -> all lanes hold l(q=lrow)
#pragma unroll
    for (int qfr = 0; qfr < 2; ++qfr) {
        lsum[qfr] += __shfl_xor(lsum[qfr], 16);
        lsum[qfr] += __shfl_xor(lsum[qfr], 32);
    }

    const int bb = bh >> 4, h = bh & 15;
#pragma unroll
    for (int qfr = 0; qfr < 2; ++qfr) {
#pragma unroll
        for (int r = 0; r < 4; ++r) {
            float inv = 1.0f / __shfl(lsum[qfr], 4 * lhi + r);
            int s = qw + qfr * 16 + 4 * lhi + r;
#pragma unroll
            for (int f = 0; f < 4; ++f)
                Ao[((long)bb * NS + s) * ND + h * HD + f * 16 + lrow] =
                    (bf16)(of[qfr][f][r] * inv);
        }
    }
}

// ---------------- launch ----------------
extern "C" void kernel_launch(void* const* d_in, const int* in_sizes, int n_in,
                              void* d_out, int out_size, void* d_ws, size_t ws_size,
                              hipStream_t stream) {
    const float* x    = (const float*)d_in[0];
    const float* Wqkv = (const float*)d_in[1];
    const float* bqkv = (const float*)d_in[2];
    const float* Wout = (const float*)d_in[3];
    const float* bout = (const float*)d_in[4];
    float* out = (float*)d_out;

    char* ws = (char*)d_ws;
    bf16* Xb  = (bf16*)(ws);                         // 16.78 MB
    bf16* Wqt = (bf16*)(ws + 16777216);              //  6.29 MB
    bf16* Wot = (bf16*)(ws + 23068672);              //  2.10 MB
    bf16* Qb  = (bf16*)(ws + 25165824);              // 16.78 MB
    bf16* Kb  = (bf16*)(ws + 41943040);              // 16.78 MB
    bf16* Vt  = (bf16*)(ws + 58720256);              // 16.78 MB
    bf16* Ab  = (bf16*)(ws + 75497472);              // 16.78 MB  (total ~92 MB)

    k_conv<<<dim3(8192), dim3(256), 0, stream>>>(x, Xb, NB * NS * ND);
    k_transconv<<<dim3(96, 32), dim3(32, 8), 0, stream>>>(Wqkv, Wqt, ND, 3 * ND);
    k_transconv<<<dim3(32, 32), dim3(32, 8), 0, stream>>>(Wout, Wot, ND, ND);

    k_gemm<0><<<dim3(24, 64), dim3(256), 0, stream>>>(
        Xb, Wqt, bqkv, Qb, Kb, Vt, NB * NS, 3 * ND, ND);

    k_attn<<<dim3(16, 64), dim3(256), 0, stream>>>(Qb, Kb, Vt, Ab);

    k_gemm<1><<<dim3(8, 64), dim3(256), 0, stream>>>(
        Ab, Wot, bout, out, nullptr, nullptr, NB * NS, ND, ND);
}